// Round 21
// baseline (289.621 us; speedup 1.0000x reference)
//
#include <hip/hip_runtime.h>
#include <stdint.h>

// Problem constants
#define BB 8
#define TT 4096
#define HH 1024
#define SS 64
#define NHH 16
#define DHH 64

typedef __attribute__((ext_vector_type(8))) short short8;
typedef __attribute__((ext_vector_type(8))) unsigned short ushortx8;
typedef __attribute__((ext_vector_type(4))) float f32x4;
typedef unsigned short u16;

#define GLOAD16(gp, lp)                                                   \
  __builtin_amdgcn_global_load_lds(                                      \
      (const __attribute__((address_space(1))) void*)(gp),               \
      (__attribute__((address_space(3))) void*)(lp), 16, 0, 0)

__device__ __forceinline__ u16 f2bf(float f) {
  union { float f; uint32_t u; } v;
  v.f = f;
  uint32_t u = v.u;
  uint32_t r = u + 0x7fffu + ((u >> 16) & 1u);
  return (u16)(r >> 16);
}

__device__ __forceinline__ float bf2f(u16 b) {
  union { uint32_t u; float f; } v;
  v.u = ((uint32_t)b) << 16;
  return v.f;
}

// Stage a 128-row x 64-col f32 tile (row stride ld) into swizzled bf16 LDS.
// LDS layout: row*64 + (slot ^ (row&7))*8, slot = k/8 (8 slots of 8 bf16 = 16B).
__device__ __forceinline__ void stage_tile(u16* lds, const float* src, int ld, int tid) {
#pragma unroll
  for (int q = 0; q < 4; ++q) {
    int slot_id = tid + (q << 8);
    int row = slot_id >> 3;
    int sl = slot_id & 7;
    const float* p = src + (size_t)row * ld + (sl << 3);
    float4 x0 = *(const float4*)(p);
    float4 x1 = *(const float4*)(p + 4);
    ushortx8 o;
    o[0] = f2bf(x0.x); o[1] = f2bf(x0.y); o[2] = f2bf(x0.z); o[3] = f2bf(x0.w);
    o[4] = f2bf(x1.x); o[5] = f2bf(x1.y); o[6] = f2bf(x1.z); o[7] = f2bf(x1.w);
    *(ushortx8*)(&lds[(row << 6) + (((sl ^ (row & 7)) << 3))]) = o;
  }
}

// Same but bf16 source (no conversion).
__device__ __forceinline__ void stage_tile_bf(u16* lds, const u16* src, int ld, int tid) {
#pragma unroll
  for (int q = 0; q < 4; ++q) {
    int slot_id = tid + (q << 8);
    int row = slot_id >> 3;
    int sl = slot_id & 7;
    ushortx8 v = *(const ushortx8*)(src + (size_t)row * ld + (sl << 3));
    *(ushortx8*)(&lds[(row << 6) + (((sl ^ (row & 7)) << 3))]) = v;
  }
}

// ---------------- pool + setup + conv fused (LDS-free: round-19 proven ~78us) ----------------
// bid < 512: pool; bid < 1024: bias-init qkv + zero cbuf + sid; else conv tiles.
__global__ __launch_bounds__(256) void conv_setup_kernel(const float* __restrict__ h,
                                                         u16* __restrict__ hbf,
                                                         const float* __restrict__ w1,
                                                         u16* __restrict__ wbf,
                                                         const float* __restrict__ ipb,
                                                         const int* __restrict__ bounds,
                                                         float* __restrict__ qkv,
                                                         float* __restrict__ cbuf,
                                                         int* __restrict__ sid,
                                                         float* __restrict__ sent) {
  int bid = blockIdx.x;
  int tid = threadIdx.x;
  if (bid < 512) {
    // ---- pool: one block per (b,s), f32 source (LLC-hot alongside conv) ----
    int bs = bid;
    int b = bs >> 6;
    int start = bounds[bs * 2];
    int end = bounds[bs * 2 + 1];
    int lo = max(start, 0), hi = min(end, TT);
    int cnt = max(hi - lo, 0);
    float inv = 1.0f / (float)max(cnt, 1);
    const float4* h4 = (const float4*)(h) + (size_t)b * TT * 256 + tid;
    float4 a0 = {0, 0, 0, 0}, a1 = {0, 0, 0, 0}, a2 = {0, 0, 0, 0}, a3 = {0, 0, 0, 0};
    int t = lo;
    for (; t + 4 <= hi; t += 4) {
      float4 v0 = h4[(size_t)(t + 0) * 256];
      float4 v1 = h4[(size_t)(t + 1) * 256];
      float4 v2 = h4[(size_t)(t + 2) * 256];
      float4 v3 = h4[(size_t)(t + 3) * 256];
      a0.x += v0.x; a0.y += v0.y; a0.z += v0.z; a0.w += v0.w;
      a1.x += v1.x; a1.y += v1.y; a1.z += v1.z; a1.w += v1.w;
      a2.x += v2.x; a2.y += v2.y; a2.z += v2.z; a2.w += v2.w;
      a3.x += v3.x; a3.y += v3.y; a3.z += v3.z; a3.w += v3.w;
    }
    for (; t < hi; ++t) {
      float4 v0 = h4[(size_t)t * 256];
      a0.x += v0.x; a0.y += v0.y; a0.z += v0.z; a0.w += v0.w;
    }
    float4 r;
    r.x = (a0.x + a1.x + a2.x + a3.x) * inv;
    r.y = (a0.y + a1.y + a2.y + a3.y) * inv;
    r.z = (a0.z + a1.z + a2.z + a3.z) * inv;
    r.w = (a0.w + a1.w + a2.w + a3.w) * inv;
    ((float4*)sent)[(size_t)bs * 256 + tid] = r;
    return;
  }
  if (bid < 1024) {
    int sidx = (bid - 512) * 256 + tid;      // 0..131071
    const int STR = 512 * 256;
    float4* qkv4 = (float4*)qkv;
    const float4* ipb4 = (const float4*)ipb;
    for (int i = sidx; i < 512 * 768; i += STR) qkv4[i] = ipb4[i % 768];
    float4 z = {0.f, 0.f, 0.f, 0.f};
    float4* cbuf4 = (float4*)cbuf;
    for (int i = sidx; i < 512 * 256; i += STR) cbuf4[i] = z;
    if (sidx < BB * TT) {
      int b = sidx >> 12, t = sidx & (TT - 1);
      int r = -1;
      for (int s = 0; s < SS; ++s) {
        int st = bounds[(b * SS + s) * 2], en = bounds[(b * SS + s) * 2 + 1];
        if (t >= st && t < en) { r = s; break; }
      }
      sid[sidx] = r;
    }
    return;
  }
  int tbid = bid - 1024;                     // 0..4223
  const float* src;
  int ld;
  u16* dst;
  if (tbid < 4096) { src = h;  ld = 1024; dst = hbf; }
  else             { src = w1; ld = 2048; dst = wbf; tbid -= 4096; }
  int rt = tbid >> 4, kt = tbid & 15;
  const float* s0 = src + (size_t)rt * 128 * ld + kt * 64;
  u16* d0 = dst + (size_t)tbid * 8192;
#pragma unroll
  for (int q = 0; q < 4; ++q) {
    int slot_id = tid + (q << 8);
    int row = slot_id >> 3;
    int sl = slot_id & 7;
    const float* p = s0 + (size_t)row * ld + (sl << 3);
    float4 x0 = *(const float4*)(p);
    float4 x1 = *(const float4*)(p + 4);
    ushortx8 o;
    o[0] = f2bf(x0.x); o[1] = f2bf(x0.y); o[2] = f2bf(x0.z); o[3] = f2bf(x0.w);
    o[4] = f2bf(x1.x); o[5] = f2bf(x1.y); o[6] = f2bf(x1.z); o[7] = f2bf(x1.w);
    *(ushortx8*)(&d0[(row << 6) + (((sl ^ (row & 7)) << 3))]) = o;
  }
}

// ---------------- qkv GEMM + M + biasp, one launch (all branches use the 32KB LDS) ----------------
//  [0,64)    M tiles: M = w1b @ out_w (1024^2, bf16 out) -> Mbf
//  [64,68)   biasp[i] = b1[i] + w1b[i,:].out_b
//  [68,452)  qkv += sent @ ipw^T, 96 tiles x K-split 4
__global__ __launch_bounds__(256) void qkvM_kernel(const float* __restrict__ sent,
                                                   const float* __restrict__ ipw,
                                                   float* __restrict__ qkv,
                                                   const float* __restrict__ w1,
                                                   const float* __restrict__ outw,
                                                   const float* __restrict__ outb,
                                                   const float* __restrict__ b1,
                                                   u16* __restrict__ Mbf,
                                                   float* __restrict__ biasp) {
  __shared__ u16 As[8192];
  __shared__ u16 Bs[8192];
  int bid = blockIdx.x;
  int tid = threadIdx.x;
  int lane = tid & 63, wid = tid >> 6;
  int wm = wid >> 1, wn = wid & 1;
  int lr = lane & 15, lg = lane >> 4;
  if (bid < 64) {
    // ---- M = w1b @ out_w: tile of 128x128, K=1024 ----
    int m0 = (bid >> 3) * 128, n0 = (bid & 7) * 128;
    f32x4 acc[4][4] = {};
    for (int r0 = 0; r0 < 1024; r0 += 64) {
      __syncthreads();
      stage_tile(As, w1 + 1024 + (size_t)m0 * 2048 + r0, 2048, tid);
      // B transposed: Bs layout row=col-of-outw, swizzled like stage_tile
      for (int u = tid; u < 1024; u += 256) {
        int rr = u >> 4, cg = (u & 15) << 3;
        const float* p = outw + (size_t)(r0 + rr) * 1024 + n0 + cg;
        float4 x0 = *(const float4*)(p);
        float4 x1 = *(const float4*)(p + 4);
        float vals[8] = {x0.x, x0.y, x0.z, x0.w, x1.x, x1.y, x1.z, x1.w};
        int rhi = rr >> 3, rlo = rr & 7;
#pragma unroll
        for (int m = 0; m < 8; ++m) {
          int cc = cg + m;
          Bs[(cc << 6) + ((rhi ^ (cc & 7)) << 3) + rlo] = f2bf(vals[m]);
        }
      }
      __syncthreads();
#pragma unroll
      for (int kk = 0; kk < 2; ++kk) {
        short8 af[4], bfr[4];
#pragma unroll
        for (int i = 0; i < 4; ++i) {
          int arow = wm * 64 + i * 16 + lr;
          int aslot = (kk * 4 + lg) ^ (arow & 7);
          af[i] = *(const short8*)(&As[(arow << 6) + (aslot << 3)]);
          int brow = wn * 64 + i * 16 + lr;
          int bslot = (kk * 4 + lg) ^ (brow & 7);
          bfr[i] = *(const short8*)(&Bs[(brow << 6) + (bslot << 3)]);
        }
#pragma unroll
        for (int i = 0; i < 4; ++i)
#pragma unroll
          for (int j = 0; j < 4; ++j)
            acc[i][j] = __builtin_amdgcn_mfma_f32_16x16x32_bf16(af[i], bfr[j], acc[i][j], 0, 0, 0);
      }
    }
#pragma unroll
    for (int i = 0; i < 4; ++i)
#pragma unroll
      for (int j = 0; j < 4; ++j)
#pragma unroll
        for (int r = 0; r < 4; ++r) {
          int row = m0 + wm * 64 + i * 16 + lg * 4 + r;
          int col = n0 + wn * 64 + j * 16 + lr;
          Mbf[(size_t)row * 1024 + col] = f2bf(acc[i][j][r]);
        }
    return;
  }
  if (bid < 68) {
    int row = (bid - 64) * 256 + tid;  // 0..1023
    const float* wrow = w1 + (size_t)row * 2048 + 1024;
    float s = b1[row];
    for (int k = 0; k < 1024; k += 4) {
      float4 wv = *(const float4*)(wrow + k);
      float4 ov = *(const float4*)(outb + k);
      s += wv.x * ov.x + wv.y * ov.y + wv.z * ov.z + wv.w * ov.w;
    }
    biasp[row] = s;
    return;
  }
  // ---- qkv tile: 96 tiles x K-split 4 ----
  {
    int t = bid - 68;                // 0..383
    int kz = t / 96;
    int tt = t - kz * 96;
    int mt = tt & 3, nt = tt >> 2;   // 4 x 24
    int m0 = mt * 128, n0 = nt * 128;
    int kbeg = kz * 256;
    f32x4 acc[4][4] = {};
    for (int k0 = kbeg; k0 < kbeg + 256; k0 += 64) {
      __syncthreads();
      stage_tile(As, sent + (size_t)m0 * HH + k0, HH, tid);
      stage_tile(Bs, ipw + (size_t)n0 * HH + k0, HH, tid);
      __syncthreads();
#pragma unroll
      for (int kk = 0; kk < 2; ++kk) {
        short8 af[4], bfr[4];
#pragma unroll
        for (int i = 0; i < 4; ++i) {
          int arow = wm * 64 + i * 16 + lr;
          int aslot = (kk * 4 + lg) ^ (arow & 7);
          af[i] = *(const short8*)(&As[(arow << 6) + (aslot << 3)]);
          int brow = wn * 64 + i * 16 + lr;
          int bslot = (kk * 4 + lg) ^ (brow & 7);
          bfr[i] = *(const short8*)(&Bs[(brow << 6) + (bslot << 3)]);
        }
#pragma unroll
        for (int i = 0; i < 4; ++i)
#pragma unroll
          for (int j = 0; j < 4; ++j)
            acc[i][j] = __builtin_amdgcn_mfma_f32_16x16x32_bf16(af[i], bfr[j], acc[i][j], 0, 0, 0);
      }
    }
#pragma unroll
    for (int i = 0; i < 4; ++i)
#pragma unroll
      for (int j = 0; j < 4; ++j)
#pragma unroll
        for (int r = 0; r < 4; ++r) {
          int row = m0 + wm * 64 + i * 16 + lg * 4 + r;
          int col = n0 + wn * 64 + j * 16 + lr;
          atomicAdd(&qkv[(size_t)row * (3 * HH) + col], acc[i][j][r]);
        }
  }
}

// ---------------- cbuf += ctx @ M^T (M bf16), K-split over blockIdx.z ----------------
__global__ __launch_bounds__(256) void gemm_btbf_atomic(const float* __restrict__ A, int lda,
                                                        const u16* __restrict__ Bm, int ldb,
                                                        float* __restrict__ C, int ldc,
                                                        int kper) {
  __shared__ u16 As[128 * 64];
  __shared__ u16 Bs[128 * 64];
  int tid = threadIdx.x;
  int m0 = blockIdx.x * 128, n0 = blockIdx.y * 128;
  int kbeg = blockIdx.z * kper;
  f32x4 acc[4][4] = {};

  for (int k0 = kbeg; k0 < kbeg + kper; k0 += 64) {
    __syncthreads();
    stage_tile(As, A + (size_t)m0 * lda + k0, lda, tid);
    stage_tile_bf(Bs, Bm + (size_t)n0 * ldb + k0, ldb, tid);
    __syncthreads();
    int lane = tid & 63, wid = tid >> 6;
    int wm = wid >> 1, wn = wid & 1;
    int lr = lane & 15, lg = lane >> 4;
#pragma unroll
    for (int kk = 0; kk < 2; ++kk) {
      short8 af[4], bfr[4];
#pragma unroll
      for (int i = 0; i < 4; ++i) {
        int arow = wm * 64 + i * 16 + lr;
        int aslot = (kk * 4 + lg) ^ (arow & 7);
        af[i] = *(const short8*)(&As[(arow << 6) + (aslot << 3)]);
        int brow = wn * 64 + i * 16 + lr;
        int bslot = (kk * 4 + lg) ^ (brow & 7);
        bfr[i] = *(const short8*)(&Bs[(brow << 6) + (bslot << 3)]);
      }
#pragma unroll
      for (int i = 0; i < 4; ++i)
#pragma unroll
        for (int j = 0; j < 4; ++j)
          acc[i][j] = __builtin_amdgcn_mfma_f32_16x16x32_bf16(af[i], bfr[j], acc[i][j], 0, 0, 0);
    }
  }

  int lane = tid & 63, wid = tid >> 6;
  int wm = wid >> 1, wn = wid & 1;
  int lr = lane & 15, lg = lane >> 4;
#pragma unroll
  for (int i = 0; i < 4; ++i)
#pragma unroll
    for (int j = 0; j < 4; ++j)
#pragma unroll
      for (int r = 0; r < 4; ++r) {
        int row = m0 + wm * 64 + i * 16 + lg * 4 + r;
        int col = n0 + wn * 64 + j * 16 + lr;
        atomicAdd(&C[(size_t)row * ldc + col], acc[i][j][r]);
      }
}

// ---------------- K4: attention over S=64 per (b, head) ----------------
#define KSW(row, col) (((row) << 6) + ((col) ^ (row)))
__global__ __launch_bounds__(256) void attn_kernel(const float* __restrict__ qkv,
                                                   float* __restrict__ ctx) {
  int bh = blockIdx.x;
  int b = bh >> 4, nh = bh & 15;
  __shared__ float q[64 * 64], k[64 * 64], v[64 * 64], s[64 * 64];
  int tid = threadIdx.x;
  const float* base = qkv + (size_t)b * SS * 3072 + nh * 64;
  for (int e = tid; e < 4096; e += 256) {
    int i = e >> 6, d = e & 63;
    q[e] = base[(size_t)i * 3072 + d];
    k[KSW(i, d)] = base[(size_t)i * 3072 + 1024 + d];
    v[e] = base[(size_t)i * 3072 + 2048 + d];
  }
  __syncthreads();
  for (int e = tid; e < 4096; e += 256) {
    int i = e >> 6, j = e & 63;
    float acc = 0.f;
#pragma unroll 8
    for (int d = 0; d < 64; ++d) acc += q[(i << 6) + d] * k[KSW(j, d)];
    s[KSW(i, j)] = acc * 0.125f;  // 1/sqrt(64)
  }
  __syncthreads();
  {
    int r = tid >> 2, sub = tid & 3;
    int j0 = sub * 16;
    float m = -1e30f;
#pragma unroll
    for (int j = 0; j < 16; ++j) m = fmaxf(m, s[KSW(r, j0 + j)]);
    m = fmaxf(m, __shfl_xor(m, 1));
    m = fmaxf(m, __shfl_xor(m, 2));
    float sum = 0.f;
#pragma unroll
    for (int j = 0; j < 16; ++j) {
      float e_ = __expf(s[KSW(r, j0 + j)] - m);
      s[KSW(r, j0 + j)] = e_;
      sum += e_;
    }
    sum += __shfl_xor(sum, 1);
    sum += __shfl_xor(sum, 2);
    float inv = 1.0f / sum;
#pragma unroll
    for (int j = 0; j < 16; ++j) s[KSW(r, j0 + j)] *= inv;
  }
  __syncthreads();
  for (int e = tid; e < 4096; e += 256) {
    int i = e >> 6, d = e & 63;
    float acc = 0.f;
#pragma unroll 8
    for (int j = 0; j < 64; ++j) acc += s[KSW(i, j)] * v[(j << 6) + d];
    ctx[((size_t)b * SS + i) * HH + nh * 64 + d] = acc;
  }
}

// ---------------- K7: partial score, 128x256 tile (round-11 proven, 85us) ----------------
// Epilogue adds biasp[col] (c_true = cbuf_raw + biasp broadcast).
__global__ __launch_bounds__(512, 4) void score_partial(const u16* __restrict__ hbf,
                                                        const u16* __restrict__ wbf,
                                                        const float* __restrict__ cbuf,
                                                        const float* __restrict__ w2,
                                                        const float* __restrict__ biasp,
                                                        const int* __restrict__ sid_arr,
                                                        float* __restrict__ score_part) {
  __shared__ u16 As[8192];
  __shared__ u16 Bs[16384];
  __shared__ float w2_lds[256];
  __shared__ float bp_lds[256];
  __shared__ int sid_lds[128];
  __shared__ float red[128];

  int tid = threadIdx.x;
  int bid = blockIdx.x;
  int x = bid & 7;
  int g = bid >> 3;              // 0..127
  int mt = x * 32 + (g >> 2);    // 0..255
  int c = g & 3;                 // N-chunk of 256 cols
  int n0 = c * 256;
  size_t g0 = (size_t)mt * 128;  // global token row
  int b = (int)(g0 >> 12);       // / T
  const u16* asrc = hbf + (size_t)mt * 16 * 8192;

  if (tid < 256) {
    w2_lds[tid] = w2[n0 + tid];
    bp_lds[tid] = biasp[n0 + tid];
  }
  if (tid < 128) {
    sid_lds[tid] = sid_arr[g0 + tid];
    red[tid] = 0.f;
  }

  int lane = tid & 63, wid = tid >> 6;  // wid 0..7
  int wm = wid >> 2, wn = wid & 3;      // 2 x 4 wave grid, each 64x64
  int lr = lane & 15, lg = lane >> 4;

  f32x4 acc[4][4] = {};
  for (int kt = 0; kt < 16; ++kt) {
    __syncthreads();  // previous iteration's LDS reads complete
    const u16* at = asrc + kt * 8192;
#pragma unroll
    for (int q = 0; q < 2; ++q) {
      int off = q * 4096 + wid * 512;   // wave-uniform u16 base
      GLOAD16(at + off + lane * 8, &As[off]);
    }
#pragma unroll
    for (int q = 0; q < 4; ++q) {
      int half = q >> 1;
      int boff = (q & 1) * 4096 + wid * 512;
      const u16* bt = wbf + ((size_t)(2 * c + half) * 16 + kt) * 8192;
      GLOAD16(bt + boff + lane * 8, &Bs[half * 8192 + boff]);
    }
    __syncthreads();  // compiler drains vmcnt(0) before barrier -> tile ready
#pragma unroll
    for (int kk = 0; kk < 2; ++kk) {
      short8 af[4], bfr[4];
#pragma unroll
      for (int i = 0; i < 4; ++i) {
        int arow = wm * 64 + i * 16 + lr;
        int aslot = (kk * 4 + lg) ^ (arow & 7);
        af[i] = *(const short8*)(&As[(arow << 6) + (aslot << 3)]);
      }
#pragma unroll
      for (int j = 0; j < 4; ++j) {
        int brow = wn * 64 + j * 16 + lr;       // 0..255
        int half = (wn * 64 + j * 16) >> 7;     // uniform per (wn,j)
        int r = brow & 127;
        int bslot = (kk * 4 + lg) ^ (r & 7);
        bfr[j] = *(const short8*)(&Bs[(half << 13) + (r << 6) + (bslot << 3)]);
      }
#pragma unroll
      for (int i = 0; i < 4; ++i)
#pragma unroll
        for (int j = 0; j < 4; ++j)
          acc[i][j] = __builtin_amdgcn_mfma_f32_16x16x32_bf16(af[i], bfr[j], acc[i][j], 0, 0, 0);
    }
  }

  // score epilogue: sp = sum_j w2[j] * relu(u + cbuf[sid,j] + biasp[j])
  float sp[4][4];
#pragma unroll
  for (int i = 0; i < 4; ++i) {
#pragma unroll
    for (int r = 0; r < 4; ++r) {
      int rowl = wm * 64 + i * 16 + lg * 4 + r;
      int s = sid_lds[rowl];
      int sc = s < 0 ? 0 : s;
      const float* crow = cbuf + ((size_t)b * SS + sc) * HH + n0;
      float accs = 0.f;
#pragma unroll
      for (int j = 0; j < 4; ++j) {
        int coll = wn * 64 + j * 16 + lr;
        float t = acc[i][j][r] + crow[coll] + bp_lds[coll];
        if (t > 0.f) accs += t * w2_lds[coll];
      }
      sp[i][r] = accs;
    }
  }

#pragma unroll
  for (int i = 0; i < 4; ++i)
#pragma unroll
    for (int r = 0; r < 4; ++r) {
      float v = sp[i][r];
      v += __shfl_xor(v, 1);
      v += __shfl_xor(v, 2);
      v += __shfl_xor(v, 4);
      v += __shfl_xor(v, 8);
      sp[i][r] = v;
    }
  if (lr == 0) {
#pragma unroll
    for (int i = 0; i < 4; ++i)
#pragma unroll
      for (int r = 0; r < 4; ++r)
        atomicAdd(&red[wm * 64 + i * 16 + lg * 4 + r], sp[i][r]);
  }
  __syncthreads();
  if (tid < 128) score_part[(size_t)c * (BB * TT) + g0 + tid] = red[tid];
}

// ---------------- K9: out = hbf * (1 + covered*(sum_c spart + b2)) ----------------
__global__ __launch_bounds__(256) void scale_kernel(const u16* __restrict__ hbf,
                                                    const float* __restrict__ score_part,
                                                    const float* __restrict__ b2,
                                                    const int* __restrict__ sid_arr,
                                                    float* __restrict__ out) {
  __shared__ float fac[16];
  int tid = threadIdx.x;
  int r0 = blockIdx.x * 16;
  if (tid < 16) {
    int t = r0 + tid;
    float s = b2[0];
#pragma unroll
    for (int c = 0; c < 4; ++c) s += score_part[(size_t)c * (BB * TT) + t];
    fac[tid] = (sid_arr[t] >= 0) ? (1.0f + s) : 1.0f;
  }
  __syncthreads();
  for (int e = tid; e < 16 * 128; e += 256) {
    int row = e >> 7, grp = e & 127;
    int kt = grp >> 3, slot = grp & 7;
    int grow = r0 + row;
    int rt = grow >> 7, r = grow & 127;
    const u16* tile = hbf + ((size_t)rt * 16 + kt) * 8192;
    ushortx8 v = *(const ushortx8*)(&tile[(r << 6) + ((slot ^ (r & 7)) << 3)]);
    float f = fac[row];
    float4 o0, o1;
    o0.x = bf2f(v[0]) * f; o0.y = bf2f(v[1]) * f; o0.z = bf2f(v[2]) * f; o0.w = bf2f(v[3]) * f;
    o1.x = bf2f(v[4]) * f; o1.y = bf2f(v[5]) * f; o1.z = bf2f(v[6]) * f; o1.w = bf2f(v[7]) * f;
    float4* dst = (float4*)(out + (size_t)grow * HH + grp * 8);
    dst[0] = o0;
    dst[1] = o1;
  }
}

extern "C" void kernel_launch(void* const* d_in, const int* in_sizes, int n_in,
                              void* d_out, int out_size, void* d_ws, size_t ws_size,
                              hipStream_t stream) {
  const float* h        = (const float*)d_in[0];
  const int*   bounds   = (const int*)d_in[1];
  const float* in_proj_w = (const float*)d_in[2];
  const float* in_proj_b = (const float*)d_in[3];
  const float* out_w    = (const float*)d_in[4];
  const float* out_b    = (const float*)d_in[5];
  const float* w1       = (const float*)d_in[6];
  const float* b1       = (const float*)d_in[7];
  const float* w2       = (const float*)d_in[8];
  const float* b2       = (const float*)d_in[9];
  float* out = (float*)d_out;

  char* ws = (char*)d_ws;
  float* sent  = (float*)(ws);                        // 2 MB
  float* qkv   = (float*)(ws + (2ull << 20));         // 6 MB
  float* ctx   = (float*)(ws + (8ull << 20));         // 2 MB
  u16*   Mbf   = (u16*)(ws + (10ull << 20));          // 2 MB (bf16 M = w1b@out_w)
  float* cbuf  = (float*)(ws + (12ull << 20));        // 2 MB
  int*   sid   = (int*)(ws + (14ull << 20));          // 128 KB
  float* biasp = (float*)(ws + (14ull << 20) + (256 << 10));  // 4 KB
  float* spart = (float*)(ws + (15ull << 20));        // 512 KB (4 chunks)
  u16*   hbf   = (u16*)(ws + (16ull << 20));          // 64 MB
  u16*   wbf   = (u16*)(ws + (80ull << 20));          // 2 MB

  // pool + bias-init/sid + conv (fused, LDS-free; pool blocks first)
  conv_setup_kernel<<<512 + 512 + 4224, 256, 0, stream>>>(
      h, hbf, w1, wbf, in_proj_b, bounds, qkv, cbuf, sid, sent);

  // qkv GEMM + M + biasp in one launch (M finishes before its consumer below)
  qkvM_kernel<<<64 + 4 + 384, 256, 0, stream>>>(
      sent, in_proj_w, qkv, w1, out_w, out_b, b1, Mbf, biasp);

  attn_kernel<<<BB * NHH, 256, 0, stream>>>(qkv, ctx);
  // cbuf = ctx @ M^T  (512 x 1024, K=1024), M bf16; biasp added in score epilogue
  gemm_btbf_atomic<<<dim3(4, 8, 4), 256, 0, stream>>>(ctx, HH, Mbf, HH, cbuf, HH, 256);

  // big GEMM partial scores: 1024 blocks (256 M-tiles x 4 N-chunks), XCD-grouped
  score_partial<<<1024, 512, 0, stream>>>(hbf, wbf, cbuf, w2, biasp, sid, spart);
  scale_kernel<<<2048, 256, 0, stream>>>(hbf, spart, b2, sid, out);
}

// Round 22
// 267.449 us; speedup vs baseline: 1.0829x; 1.0829x over previous
//
#include <hip/hip_runtime.h>
#include <stdint.h>

// Problem constants
#define BB 8
#define TT 4096
#define HH 1024
#define SS 64
#define NHH 16
#define DHH 64

typedef __attribute__((ext_vector_type(8))) short short8;
typedef __attribute__((ext_vector_type(8))) unsigned short ushortx8;
typedef __attribute__((ext_vector_type(4))) float f32x4;
typedef unsigned short u16;

#define GLOAD16(gp, lp)                                                   \
  __builtin_amdgcn_global_load_lds(                                      \
      (const __attribute__((address_space(1))) void*)(gp),               \
      (__attribute__((address_space(3))) void*)(lp), 16, 0, 0)

__device__ __forceinline__ u16 f2bf(float f) {
  union { float f; uint32_t u; } v;
  v.f = f;
  uint32_t u = v.u;
  uint32_t r = u + 0x7fffu + ((u >> 16) & 1u);
  return (u16)(r >> 16);
}

__device__ __forceinline__ float bf2f(u16 b) {
  union { uint32_t u; float f; } v;
  v.u = ((uint32_t)b) << 16;
  return v.f;
}

// Stage a 128-row x 64-col f32 tile (row stride ld) into swizzled bf16 LDS.
// LDS layout: row*64 + (slot ^ (row&7))*8, slot = k/8 (8 slots of 8 bf16 = 16B).
__device__ __forceinline__ void stage_tile(u16* lds, const float* src, int ld, int tid) {
#pragma unroll
  for (int q = 0; q < 4; ++q) {
    int slot_id = tid + (q << 8);
    int row = slot_id >> 3;
    int sl = slot_id & 7;
    const float* p = src + (size_t)row * ld + (sl << 3);
    float4 x0 = *(const float4*)(p);
    float4 x1 = *(const float4*)(p + 4);
    ushortx8 o;
    o[0] = f2bf(x0.x); o[1] = f2bf(x0.y); o[2] = f2bf(x0.z); o[3] = f2bf(x0.w);
    o[4] = f2bf(x1.x); o[5] = f2bf(x1.y); o[6] = f2bf(x1.z); o[7] = f2bf(x1.w);
    *(ushortx8*)(&lds[(row << 6) + (((sl ^ (row & 7)) << 3))]) = o;
  }
}

// ---------------- pool + setup + conv fused ----------------
// Pool blocks FIRST (long-latency; overlap under conv stream — r19 proven).
// bid < 512: pool from f32 h; bid < 1024: bias-init + sid; else conv tiles.
__global__ __launch_bounds__(256) void conv_setup_kernel(const float* __restrict__ h,
                                                         u16* __restrict__ hbf,
                                                         const float* __restrict__ w1,
                                                         u16* __restrict__ wbf,
                                                         const float* __restrict__ ipb,
                                                         const float* __restrict__ outb,
                                                         const float* __restrict__ b1,
                                                         const int* __restrict__ bounds,
                                                         float* __restrict__ qkv,
                                                         float* __restrict__ att,
                                                         float* __restrict__ cbuf,
                                                         int* __restrict__ sid,
                                                         float* __restrict__ sent) {
  int bid = blockIdx.x;
  int tid = threadIdx.x;
  if (bid < 512) {
    // ---- pool: one block per (b,s), f32 source (LLC-hot alongside conv) ----
    int bs = bid;
    int b = bs >> 6;
    int start = bounds[bs * 2];
    int end = bounds[bs * 2 + 1];
    int lo = max(start, 0), hi = min(end, TT);
    int cnt = max(hi - lo, 0);
    float inv = 1.0f / (float)max(cnt, 1);
    const float4* h4 = (const float4*)(h) + (size_t)b * TT * 256 + tid;
    float4 a0 = {0, 0, 0, 0}, a1 = {0, 0, 0, 0}, a2 = {0, 0, 0, 0}, a3 = {0, 0, 0, 0};
    int t = lo;
    for (; t + 4 <= hi; t += 4) {
      float4 v0 = h4[(size_t)(t + 0) * 256];
      float4 v1 = h4[(size_t)(t + 1) * 256];
      float4 v2 = h4[(size_t)(t + 2) * 256];
      float4 v3 = h4[(size_t)(t + 3) * 256];
      a0.x += v0.x; a0.y += v0.y; a0.z += v0.z; a0.w += v0.w;
      a1.x += v1.x; a1.y += v1.y; a1.z += v1.z; a1.w += v1.w;
      a2.x += v2.x; a2.y += v2.y; a2.z += v2.z; a2.w += v2.w;
      a3.x += v3.x; a3.y += v3.y; a3.z += v3.z; a3.w += v3.w;
    }
    for (; t < hi; ++t) {
      float4 v0 = h4[(size_t)t * 256];
      a0.x += v0.x; a0.y += v0.y; a0.z += v0.z; a0.w += v0.w;
    }
    float4 r;
    r.x = (a0.x + a1.x + a2.x + a3.x) * inv;
    r.y = (a0.y + a1.y + a2.y + a3.y) * inv;
    r.z = (a0.z + a1.z + a2.z + a3.z) * inv;
    r.w = (a0.w + a1.w + a2.w + a3.w) * inv;
    ((float4*)sent)[(size_t)bs * 256 + tid] = r;
    return;
  }
  if (bid < 1024) {
    int sidx = (bid - 512) * 256 + tid;      // 0..131071
    const int STR = 512 * 256;
    for (int i = sidx; i < 512 * 3072; i += STR) qkv[i] = ipb[i % 3072];
    for (int i = sidx; i < 512 * 1024; i += STR) att[i] = outb[i & 1023];
    for (int i = sidx; i < 512 * 1024; i += STR) cbuf[i] = b1[i & 1023];
    if (sidx < BB * TT) {
      int b = sidx >> 12, t = sidx & (TT - 1);
      int r = -1;
      for (int s = 0; s < SS; ++s) {
        int st = bounds[(b * SS + s) * 2], en = bounds[(b * SS + s) * 2 + 1];
        if (t >= st && t < en) { r = s; break; }
      }
      sid[sidx] = r;
    }
    return;
  }
  int tbid = bid - 1024;                     // 0..4223
  const float* src;
  int ld;
  u16* dst;
  if (tbid < 4096) { src = h;  ld = 1024; dst = hbf; }
  else             { src = w1; ld = 2048; dst = wbf; tbid -= 4096; }
  int rt = tbid >> 4, kt = tbid & 15;
  const float* s0 = src + (size_t)rt * 128 * ld + kt * 64;
  u16* d0 = dst + (size_t)tbid * 8192;
#pragma unroll
  for (int q = 0; q < 4; ++q) {
    int slot_id = tid + (q << 8);
    int row = slot_id >> 3;
    int sl = slot_id & 7;
    const float* p = s0 + (size_t)row * ld + (sl << 3);
    float4 x0 = *(const float4*)(p);
    float4 x1 = *(const float4*)(p + 4);
    ushortx8 o;
    o[0] = f2bf(x0.x); o[1] = f2bf(x0.y); o[2] = f2bf(x0.z); o[3] = f2bf(x0.w);
    o[4] = f2bf(x1.x); o[5] = f2bf(x1.y); o[6] = f2bf(x1.z); o[7] = f2bf(x1.w);
    *(ushortx8*)(&d0[(row << 6) + (((sl ^ (row & 7)) << 3))]) = o;
  }
}

// ---------------- C += A @ B^T via atomics, K-split over blockIdx.z ----------------
__global__ __launch_bounds__(256) void gemm_bt_atomic(const float* __restrict__ A, int lda,
                                                      const float* __restrict__ Bm, int ldb,
                                                      float* __restrict__ C, int ldc,
                                                      int kper) {
  __shared__ u16 As[128 * 64];
  __shared__ u16 Bs[128 * 64];
  int tid = threadIdx.x;
  int m0 = blockIdx.x * 128, n0 = blockIdx.y * 128;
  int kbeg = blockIdx.z * kper;
  f32x4 acc[4][4] = {};

  for (int k0 = kbeg; k0 < kbeg + kper; k0 += 64) {
    __syncthreads();
    stage_tile(As, A + (size_t)m0 * lda + k0, lda, tid);
    stage_tile(Bs, Bm + (size_t)n0 * ldb + k0, ldb, tid);
    __syncthreads();
    int lane = tid & 63, wid = tid >> 6;
    int wm = wid >> 1, wn = wid & 1;
    int lr = lane & 15, lg = lane >> 4;
#pragma unroll
    for (int kk = 0; kk < 2; ++kk) {
      short8 af[4], bfr[4];
#pragma unroll
      for (int i = 0; i < 4; ++i) {
        int arow = wm * 64 + i * 16 + lr;
        int aslot = (kk * 4 + lg) ^ (arow & 7);
        af[i] = *(const short8*)(&As[(arow << 6) + (aslot << 3)]);
        int brow = wn * 64 + i * 16 + lr;
        int bslot = (kk * 4 + lg) ^ (brow & 7);
        bfr[i] = *(const short8*)(&Bs[(brow << 6) + (bslot << 3)]);
      }
#pragma unroll
      for (int i = 0; i < 4; ++i)
#pragma unroll
        for (int j = 0; j < 4; ++j)
          acc[i][j] = __builtin_amdgcn_mfma_f32_16x16x32_bf16(af[i], bfr[j], acc[i][j], 0, 0, 0);
    }
  }

  int lane = tid & 63, wid = tid >> 6;
  int wm = wid >> 1, wn = wid & 1;
  int lr = lane & 15, lg = lane >> 4;
#pragma unroll
  for (int i = 0; i < 4; ++i)
#pragma unroll
    for (int j = 0; j < 4; ++j)
#pragma unroll
      for (int r = 0; r < 4; ++r) {
        int row = m0 + wm * 64 + i * 16 + lg * 4 + r;
        int col = n0 + wn * 64 + j * 16 + lr;
        atomicAdd(&C[(size_t)row * ldc + col], acc[i][j][r]);
      }
}

// ---------------- K4: attention over S=64 per (b, head) ----------------
// k and s are XOR-swizzled: idx(row,col) = row*64 + (col ^ row) -> QK^T's
// per-d column read spreads over banks (r17: 7.9M conflicts with linear layout).
#define KSW(row, col) (((row) << 6) + ((col) ^ (row)))
__global__ __launch_bounds__(256) void attn_kernel(const float* __restrict__ qkv,
                                                   float* __restrict__ ctx) {
  int bh = blockIdx.x;
  int b = bh >> 4, nh = bh & 15;
  __shared__ float q[64 * 64], k[64 * 64], v[64 * 64], s[64 * 64];
  int tid = threadIdx.x;
  const float* base = qkv + (size_t)b * SS * 3072 + nh * 64;
  for (int e = tid; e < 4096; e += 256) {
    int i = e >> 6, d = e & 63;
    q[e] = base[(size_t)i * 3072 + d];
    k[KSW(i, d)] = base[(size_t)i * 3072 + 1024 + d];
    v[e] = base[(size_t)i * 3072 + 2048 + d];
  }
  __syncthreads();
  for (int e = tid; e < 4096; e += 256) {
    int i = e >> 6, j = e & 63;
    float acc = 0.f;
#pragma unroll 8
    for (int d = 0; d < 64; ++d) acc += q[(i << 6) + d] * k[KSW(j, d)];
    s[KSW(i, j)] = acc * 0.125f;  // 1/sqrt(64)
  }
  __syncthreads();
  {
    int r = tid >> 2, sub = tid & 3;
    int j0 = sub * 16;
    float m = -1e30f;
#pragma unroll
    for (int j = 0; j < 16; ++j) m = fmaxf(m, s[KSW(r, j0 + j)]);
    m = fmaxf(m, __shfl_xor(m, 1));
    m = fmaxf(m, __shfl_xor(m, 2));
    float sum = 0.f;
#pragma unroll
    for (int j = 0; j < 16; ++j) {
      float e_ = __expf(s[KSW(r, j0 + j)] - m);
      s[KSW(r, j0 + j)] = e_;
      sum += e_;
    }
    sum += __shfl_xor(sum, 1);
    sum += __shfl_xor(sum, 2);
    float inv = 1.0f / sum;
#pragma unroll
    for (int j = 0; j < 16; ++j) s[KSW(r, j0 + j)] *= inv;
  }
  __syncthreads();
  for (int e = tid; e < 4096; e += 256) {
    int i = e >> 6, d = e & 63;
    float acc = 0.f;
#pragma unroll 8
    for (int j = 0; j < 64; ++j) acc += s[KSW(i, j)] * v[(j << 6) + d];
    ctx[((size_t)b * SS + i) * HH + nh * 64 + d] = acc;
  }
}

// ---------------- K7: partial score, 128x256 tile (round-11/19 proven, 85us) ----------------
__global__ __launch_bounds__(512, 4) void score_partial(const u16* __restrict__ hbf,
                                                        const u16* __restrict__ wbf,
                                                        const float* __restrict__ cbuf,
                                                        const float* __restrict__ w2,
                                                        const int* __restrict__ sid_arr,
                                                        float* __restrict__ score_part) {
  __shared__ u16 As[8192];
  __shared__ u16 Bs[16384];
  __shared__ float w2_lds[256];
  __shared__ int sid_lds[128];
  __shared__ float red[128];

  int tid = threadIdx.x;
  int bid = blockIdx.x;
  int x = bid & 7;
  int g = bid >> 3;              // 0..127
  int mt = x * 32 + (g >> 2);    // 0..255
  int c = g & 3;                 // N-chunk of 256 cols
  int n0 = c * 256;
  size_t g0 = (size_t)mt * 128;  // global token row
  int b = (int)(g0 >> 12);       // / T
  const u16* asrc = hbf + (size_t)mt * 16 * 8192;

  if (tid < 256) w2_lds[tid] = w2[n0 + tid];
  if (tid < 128) {
    sid_lds[tid] = sid_arr[g0 + tid];
    red[tid] = 0.f;
  }

  int lane = tid & 63, wid = tid >> 6;  // wid 0..7
  int wm = wid >> 2, wn = wid & 3;      // 2 x 4 wave grid, each 64x64
  int lr = lane & 15, lg = lane >> 4;

  f32x4 acc[4][4] = {};
  for (int kt = 0; kt < 16; ++kt) {
    __syncthreads();  // previous iteration's LDS reads complete
    const u16* at = asrc + kt * 8192;
#pragma unroll
    for (int q = 0; q < 2; ++q) {
      int off = q * 4096 + wid * 512;   // wave-uniform u16 base
      GLOAD16(at + off + lane * 8, &As[off]);
    }
#pragma unroll
    for (int q = 0; q < 4; ++q) {
      int half = q >> 1;
      int boff = (q & 1) * 4096 + wid * 512;
      const u16* bt = wbf + ((size_t)(2 * c + half) * 16 + kt) * 8192;
      GLOAD16(bt + boff + lane * 8, &Bs[half * 8192 + boff]);
    }
    __syncthreads();  // compiler drains vmcnt(0) before barrier -> tile ready
#pragma unroll
    for (int kk = 0; kk < 2; ++kk) {
      short8 af[4], bfr[4];
#pragma unroll
      for (int i = 0; i < 4; ++i) {
        int arow = wm * 64 + i * 16 + lr;
        int aslot = (kk * 4 + lg) ^ (arow & 7);
        af[i] = *(const short8*)(&As[(arow << 6) + (aslot << 3)]);
      }
#pragma unroll
      for (int j = 0; j < 4; ++j) {
        int brow = wn * 64 + j * 16 + lr;       // 0..255
        int half = (wn * 64 + j * 16) >> 7;     // uniform per (wn,j)
        int r = brow & 127;
        int bslot = (kk * 4 + lg) ^ (r & 7);
        bfr[j] = *(const short8*)(&Bs[(half << 13) + (r << 6) + (bslot << 3)]);
      }
#pragma unroll
      for (int i = 0; i < 4; ++i)
#pragma unroll
        for (int j = 0; j < 4; ++j)
          acc[i][j] = __builtin_amdgcn_mfma_f32_16x16x32_bf16(af[i], bfr[j], acc[i][j], 0, 0, 0);
    }
  }

  // score epilogue: sp = sum_j w2[j] * relu(u + c[sid, j]) over this wave's 64 cols
  float sp[4][4];
#pragma unroll
  for (int i = 0; i < 4; ++i) {
#pragma unroll
    for (int r = 0; r < 4; ++r) {
      int rowl = wm * 64 + i * 16 + lg * 4 + r;
      int s = sid_lds[rowl];
      int sc = s < 0 ? 0 : s;
      const float* crow = cbuf + ((size_t)b * SS + sc) * HH + n0;
      float accs = 0.f;
#pragma unroll
      for (int j = 0; j < 4; ++j) {
        int coll = wn * 64 + j * 16 + lr;
        float t = acc[i][j][r] + crow[coll];
        if (t > 0.f) accs += t * w2_lds[coll];
      }
      sp[i][r] = accs;
    }
  }

#pragma unroll
  for (int i = 0; i < 4; ++i)
#pragma unroll
    for (int r = 0; r < 4; ++r) {
      float v = sp[i][r];
      v += __shfl_xor(v, 1);
      v += __shfl_xor(v, 2);
      v += __shfl_xor(v, 4);
      v += __shfl_xor(v, 8);
      sp[i][r] = v;
    }
  if (lr == 0) {
#pragma unroll
    for (int i = 0; i < 4; ++i)
#pragma unroll
      for (int r = 0; r < 4; ++r)
        atomicAdd(&red[wm * 64 + i * 16 + lg * 4 + r], sp[i][r]);
  }
  __syncthreads();
  if (tid < 128) score_part[(size_t)c * (BB * TT) + g0 + tid] = red[tid];
}

// ---------------- K9: out = hbf * (1 + covered*(sum_c spart + b2)) ----------------
__global__ __launch_bounds__(256) void scale_kernel(const u16* __restrict__ hbf,
                                                    const float* __restrict__ score_part,
                                                    const float* __restrict__ b2,
                                                    const int* __restrict__ sid_arr,
                                                    float* __restrict__ out) {
  __shared__ float fac[16];
  int tid = threadIdx.x;
  int r0 = blockIdx.x * 16;
  if (tid < 16) {
    int t = r0 + tid;
    float s = b2[0];
#pragma unroll
    for (int c = 0; c < 4; ++c) s += score_part[(size_t)c * (BB * TT) + t];
    fac[tid] = (sid_arr[t] >= 0) ? (1.0f + s) : 1.0f;
  }
  __syncthreads();
  for (int e = tid; e < 16 * 128; e += 256) {
    int row = e >> 7, grp = e & 127;
    int kt = grp >> 3, slot = grp & 7;
    int grow = r0 + row;
    int rt = grow >> 7, r = grow & 127;
    const u16* tile = hbf + ((size_t)rt * 16 + kt) * 8192;
    ushortx8 v = *(const ushortx8*)(&tile[(r << 6) + ((slot ^ (r & 7)) << 3)]);
    float f = fac[row];
    float4 o0, o1;
    o0.x = bf2f(v[0]) * f; o0.y = bf2f(v[1]) * f; o0.z = bf2f(v[2]) * f; o0.w = bf2f(v[3]) * f;
    o1.x = bf2f(v[4]) * f; o1.y = bf2f(v[5]) * f; o1.z = bf2f(v[6]) * f; o1.w = bf2f(v[7]) * f;
    float4* dst = (float4*)(out + (size_t)grow * HH + grp * 8);
    dst[0] = o0;
    dst[1] = o1;
  }
}

extern "C" void kernel_launch(void* const* d_in, const int* in_sizes, int n_in,
                              void* d_out, int out_size, void* d_ws, size_t ws_size,
                              hipStream_t stream) {
  const float* h        = (const float*)d_in[0];
  const int*   bounds   = (const int*)d_in[1];
  const float* in_proj_w = (const float*)d_in[2];
  const float* in_proj_b = (const float*)d_in[3];
  const float* out_w    = (const float*)d_in[4];
  const float* out_b    = (const float*)d_in[5];
  const float* w1       = (const float*)d_in[6];
  const float* b1       = (const float*)d_in[7];
  const float* w2       = (const float*)d_in[8];
  const float* b2       = (const float*)d_in[9];
  float* out = (float*)d_out;

  char* ws = (char*)d_ws;
  float* sent  = (float*)(ws);                        // 2 MB
  float* qkv   = (float*)(ws + (2ull << 20));         // 6 MB
  float* ctx   = (float*)(ws + (8ull << 20));         // 2 MB
  float* att   = (float*)(ws + (10ull << 20));        // 2 MB
  float* cbuf  = (float*)(ws + (12ull << 20));        // 2 MB
  int*   sid   = (int*)(ws + (14ull << 20));          // 128 KB
  float* spart = (float*)(ws + (15ull << 20));        // 512 KB (4 chunks)
  u16*   hbf   = (u16*)(ws + (16ull << 20));          // 64 MB
  u16*   wbf   = (u16*)(ws + (80ull << 20));          // 2 MB

  // pool + bias-init/sid + conv (fused; pool blocks FIRST to avoid the tail)
  conv_setup_kernel<<<512 + 512 + 4224, 256, 0, stream>>>(
      h, hbf, w1, wbf, in_proj_b, out_b, b1, bounds, qkv, att, cbuf, sid, sent);

  // qkv = sent @ in_proj_w^T + in_proj_b   (512 x 3072, K=1024), K-split x4
  gemm_bt_atomic<<<dim3(4, 24, 4), 256, 0, stream>>>(sent, HH, in_proj_w, HH, qkv, 3 * HH, 256);
  attn_kernel<<<BB * NHH, 256, 0, stream>>>(qkv, ctx);
  // attended = ctx @ out_w^T + out_b       (512 x 1024, K=1024), K-split x4
  gemm_bt_atomic<<<dim3(4, 8, 4), 256, 0, stream>>>(ctx, HH, out_w, HH, att, HH, 256);
  // c = attended @ w1b^T + b1              (512 x 1024, K=1024), w1b = w1[:, H:]
  gemm_bt_atomic<<<dim3(4, 8, 4), 256, 0, stream>>>(att, HH, w1 + HH, 2 * HH, cbuf, HH, 256);

  // big GEMM partial scores: 1024 blocks (256 M-tiles x 4 N-chunks), XCD-grouped
  score_partial<<<1024, 512, 0, stream>>>(hbf, wbf, cbuf, w2, sid, spart);
  scale_kernel<<<2048, 256, 0, stream>>>(hbf, spart, b2, sid, out);
}